// Round 7
// baseline (210.879 us; speedup 1.0000x reference)
//
#include <hip/hip_runtime.h>

#define T_DIM 256
#define C_DIM 384
#define H_DIM 64

typedef __attribute__((ext_vector_type(4))) float f32x4;
typedef __attribute__((ext_vector_type(8))) short bf16x8;
typedef unsigned short u16;

// fp32 -> bf16 round-to-nearest-even (finite inputs)
__device__ __forceinline__ u16 f2b(float f) {
  unsigned u = __float_as_uint(f);
  u = (u + 0x7FFFu + ((u >> 16) & 1u)) >> 16;
  return (u16)u;
}
// packed f32x2 -> bf16x2: lo = bf16(a), hi = bf16(b)
__device__ __forceinline__ unsigned pkbf(float a, float b) {
  unsigned r;
  asm("v_cvt_pk_bf16_f32 %0, %1, %2" : "=v"(r) : "v"(a), "v"(b));
  return r;
}

// Swizzled element offsets (u16 units). Writes and reads share the permutation.
__device__ __forceinline__ int sw64(int r, int c)  { return r * 64  + (c ^ ((r & 7) << 3)); }
__device__ __forceinline__ int sw256(int h, int t) { return h * 256 + (t ^ ((h & 7) << 3)); }
__device__ __forceinline__ int sw32(int r, int c)  { return r * 32  + (c ^ (((r >> 1) & 3) << 3)); }

// One block per batch. 512 threads = 8 waves. LDS = 64 KB -> 2 blocks/CU.
// Phase 1 (R6-proven): QKV = x_b @ [Wq|Wk|Wv], M=256 N=192 K=384, K-step 32.
//   Staging xs[256][32]+wsT[192][32] (28 KB) overlays the ks/vT region.
// Handoff: Q never goes to a shared buffer -- each wave transposes its own
//   32 Q-rows D->B via a private 4 KB slab (overlaid on dead staging space).
// Phase 2: swapped-operand flash attention: S^T = mfma(K, Q) makes q lane-local
//   (col=lr); softmax reduce = 2 shfls; P D->A transpose for PV = pure g-group
//   shfl exchange (no LDS, no fences inside the j-loop).
__global__ __launch_bounds__(512, 4)
void head_fused(const float* __restrict__ x,
                const float* __restrict__ Wk,
                const float* __restrict__ Wq,
                const float* __restrict__ Wv,
                float* __restrict__ out)
{
  __shared__ u16 sh[32768];   // 64 KB union:
  // phase 1: xs = sh[0..8192) [256][32] sw32; wsT = sh[8192..14336) [192][32] sw32
  // handoff: per-wave Q slab at sh[wv*2048 .. +2048) [32][64] sw64
  // phase 2: ks = sh[0..16384) [256][64] sw64; vT = sh[16384..32768) [64][256] sw256
  u16* xs  = sh;
  u16* wsT = sh + 8192;
  u16* ks  = sh;
  u16* vT  = sh + 16384;

  const int tid  = threadIdx.x;
  const int wv   = tid >> 6;
  const int lane = tid & 63;
  const int g    = lane >> 4;
  const int lr   = lane & 15;
  const int b    = blockIdx.x;

  const float* xb = x + (size_t)b * (T_DIM * C_DIM);

  // ---------------- Phase 1: QKV projection (R6 verbatim) ----------------
  int xr[4], xc[4];
#pragma unroll
  for (int it = 0; it < 4; ++it) {
    int idx = tid + it * 512;
    xr[it] = idx >> 3;
    xc[it] = (idx & 7) * 4;
  }
  int wrow[3], wcc[3];
  const float* wsrc[3];
#pragma unroll
  for (int it = 0; it < 3; ++it) {
    int idx = tid + it * 512;          // 0..1535
    int q   = idx >> 5;                // row-quad 0..47
    int cc  = idx & 31;                // col 0..31
    int seg = q >> 4;                  // 0:Q 1:K 2:V
    int hq  = q & 15;
    wrow[it] = seg * 64 + hq * 4;
    wcc[it]  = cc;
    wsrc[it] = ((seg == 0) ? Wq : (seg == 1) ? Wk : Wv) + hq * 4;
  }

  f32x4 acc[2][12];
#pragma unroll
  for (int mi = 0; mi < 2; ++mi)
#pragma unroll
    for (int nj = 0; nj < 12; ++nj)
      acc[mi][nj] = (f32x4){0.f, 0.f, 0.f, 0.f};

  f32x4 px[4], pwv[3];
#pragma unroll
  for (int it = 0; it < 4; ++it)
    px[it] = *reinterpret_cast<const f32x4*>(xb + xr[it] * C_DIM + xc[it]);
#pragma unroll
  for (int it = 0; it < 3; ++it)
    pwv[it] = *reinterpret_cast<const f32x4*>(wsrc[it] + wcc[it] * H_DIM);

  for (int kt = 0; kt < 12; ++kt) {
    __syncthreads();
#pragma unroll
    for (int it = 0; it < 4; ++it) {
      unsigned p0 = (unsigned)f2b(px[it][0]) | ((unsigned)f2b(px[it][1]) << 16);
      unsigned p1 = (unsigned)f2b(px[it][2]) | ((unsigned)f2b(px[it][3]) << 16);
      uint2 pv; pv.x = p0; pv.y = p1;
      *reinterpret_cast<uint2*>(&xs[sw32(xr[it], xc[it])]) = pv;
    }
#pragma unroll
    for (int it = 0; it < 3; ++it) {
      wsT[sw32(wrow[it] + 0, wcc[it])] = f2b(pwv[it][0]);
      wsT[sw32(wrow[it] + 1, wcc[it])] = f2b(pwv[it][1]);
      wsT[sw32(wrow[it] + 2, wcc[it])] = f2b(pwv[it][2]);
      wsT[sw32(wrow[it] + 3, wcc[it])] = f2b(pwv[it][3]);
    }
    if (kt < 11) {
      int kk = (kt + 1) * 32;
#pragma unroll
      for (int it = 0; it < 4; ++it)
        px[it] = *reinterpret_cast<const f32x4*>(xb + xr[it] * C_DIM + kk + xc[it]);
#pragma unroll
      for (int it = 0; it < 3; ++it)
        pwv[it] = *reinterpret_cast<const f32x4*>(wsrc[it] + (kk + wcc[it]) * H_DIM);
    }
    __syncthreads();

    bf16x8 afr[2];
#pragma unroll
    for (int mi = 0; mi < 2; ++mi)
      afr[mi] = *reinterpret_cast<const bf16x8*>(&xs[sw32(wv * 32 + mi * 16 + lr, g * 8)]);
#pragma unroll
    for (int nj = 0; nj < 12; ++nj) {
      bf16x8 bfr = *reinterpret_cast<const bf16x8*>(&wsT[sw32(nj * 16 + lr, g * 8)]);
#pragma unroll
      for (int mi = 0; mi < 2; ++mi)
        acc[mi][nj] = __builtin_amdgcn_mfma_f32_16x16x32_bf16(afr[mi], bfr, acc[mi][nj], 0, 0, 0);
    }
  }

  // ---------------- Handoff ----------------
  __syncthreads();   // all waves' staging reads done; staging region now dead

  // (1) own Q rows D->slab (acc nj 0..3 hold Q[32wv + 16mi + 4g+e][16nj+lr])
  u16* slab = sh + wv * 2048;   // [32][64] sw64, wave-private
#pragma unroll
  for (int mi = 0; mi < 2; ++mi)
#pragma unroll
    for (int nj = 0; nj < 4; ++nj)
#pragma unroll
      for (int e = 0; e < 4; ++e)
        slab[sw64(mi * 16 + g * 4 + e, nj * 16 + lr)] = f2b(acc[mi][nj][e]);
  asm volatile("s_waitcnt lgkmcnt(0)" ::: "memory");

  // (2) read Q as B-fragments: qf[mi][kb][e] = Q[32wv+16mi+lr][32kb+8g+e]
  bf16x8 qf[2][2];
#pragma unroll
  for (int mi = 0; mi < 2; ++mi)
#pragma unroll
    for (int kb = 0; kb < 2; ++kb)
      qf[mi][kb] = *reinterpret_cast<const bf16x8*>(&slab[sw64(mi * 16 + lr, kb * 32 + g * 8)]);
  __syncthreads();   // all slab reads done before K/V scatter overwrites the region

  // (3) scatter K,V fragments (acc nj 4..11) into ks/vT
#pragma unroll
  for (int mi = 0; mi < 2; ++mi)
#pragma unroll
    for (int nj = 4; nj < 12; ++nj)
#pragma unroll
      for (int e = 0; e < 4; ++e) {
        int r = wv * 32 + mi * 16 + g * 4 + e;
        int n = nj * 16 + lr;
        u16 val = f2b(acc[mi][nj][e]);
        if (n < 128) ks[sw64(r, n - 64)] = val;
        else         vT[sw256(n - 128, r)] = val;
      }
  __syncthreads();

  // ---------------- Phase 2: swapped-operand causal flash attention ----------------
  const int r0   = wv * 32;
  const int jmax = wv >> 1;

  f32x4 o[2][4];              // O D-layout: row q-local = 16mi+4g+e, col h = 16nh+lr
  float m_run[2], l_run[2];   // per-lane stats for q = r0 + 16mi + lr
#pragma unroll
  for (int mi = 0; mi < 2; ++mi) {
    m_run[mi] = -__builtin_inff();
    l_run[mi] = 0.f;
#pragma unroll
    for (int nh = 0; nh < 4; ++nh) o[mi][nh] = (f32x4){0.f, 0.f, 0.f, 0.f};
  }

  for (int j = 0; j <= jmax; ++j) {
    // S^T tile: sT[mi][ni][e] = S[q = r0+16mi+lr][kv = 64j+16ni+4g+e]
    f32x4 sT[2][4];
#pragma unroll
    for (int mi = 0; mi < 2; ++mi)
#pragma unroll
      for (int ni = 0; ni < 4; ++ni)
        sT[mi][ni] = (f32x4){0.f, 0.f, 0.f, 0.f};
#pragma unroll
    for (int kb = 0; kb < 2; ++kb) {
#pragma unroll
      for (int ni = 0; ni < 4; ++ni) {
        // A = K: row = kv-local = lr, k = c = 32kb+8g+e
        bf16x8 kf = *reinterpret_cast<const bf16x8*>(&ks[sw64(j * 64 + ni * 16 + lr, kb * 32 + g * 8)]);
#pragma unroll
        for (int mi = 0; mi < 2; ++mi)
          sT[mi][ni] = __builtin_amdgcn_mfma_f32_16x16x32_bf16(kf, qf[mi][kb], sT[mi][ni], 0, 0, 0);
      }
    }

    // scale + causal mask + per-row (=per-lane-q) softmax
#pragma unroll
    for (int mi = 0; mi < 2; ++mi) {
      const int q = r0 + mi * 16 + lr;
      float pm = -__builtin_inff();
#pragma unroll
      for (int ni = 0; ni < 4; ++ni)
#pragma unroll
        for (int e = 0; e < 4; ++e) {
          float v = sT[mi][ni][e] * 0.125f;
          int kv = j * 64 + ni * 16 + g * 4 + e;
          v = (kv > q) ? -__builtin_inff() : v;
          sT[mi][ni][e] = v;
          pm = fmaxf(pm, v);
        }
      // row spread over the 4 g-copies of lane lr -> 2-step reduce
      pm = fmaxf(pm, __shfl_xor(pm, 16));
      pm = fmaxf(pm, __shfl_xor(pm, 32));

      float mn = fmaxf(m_run[mi], pm);
      float alpha = __expf(m_run[mi] - mn);   // first tile: exp(-inf)=0
      m_run[mi] = mn;
      float rs = 0.f;
#pragma unroll
      for (int ni = 0; ni < 4; ++ni)
#pragma unroll
        for (int e = 0; e < 4; ++e) {
          float p = __expf(sT[mi][ni][e] - mn);  // masked: exp(-inf)=0
          sT[mi][ni][e] = p;
          rs += p;
        }
      rs += __shfl_xor(rs, 16);
      rs += __shfl_xor(rs, 32);
      l_run[mi] = l_run[mi] * alpha + rs;

      // rescale O (alpha for q-row 16mi+4g+e lives at lane lr' = 4g+e)
#pragma unroll
      for (int e = 0; e < 4; ++e) {
        float am = __shfl(alpha, g * 4 + e);
#pragma unroll
        for (int nh = 0; nh < 4; ++nh) o[mi][nh][e] *= am;
      }
    }

    // P D->A transpose via g-group exchange (no LDS):
    // pa[mi][kb] word w (= kv pair 32kb+8g+2w) <- pk[ni][half] of lane 16*gsrc+lr
    union PA { unsigned w[4]; bf16x8 v; };
    PA pa[2][2];
#pragma unroll
    for (int mi = 0; mi < 2; ++mi) {
      unsigned pk[4][2];
#pragma unroll
      for (int ni = 0; ni < 4; ++ni) {
        pk[ni][0] = pkbf(sT[mi][ni][0], sT[mi][ni][1]);  // kv {16ni+4g+0, +1}
        pk[ni][1] = pkbf(sT[mi][ni][2], sT[mi][ni][3]);  // kv {16ni+4g+2, +3}
      }
#pragma unroll
      for (int kb = 0; kb < 2; ++kb)
#pragma unroll
        for (int w = 0; w < 4; ++w) {
          int sl = ((2 * g + (w >> 1)) & 3) * 16 + lr;   // source lane
          unsigned lo = __shfl(pk[2 * kb + 0][w & 1], sl);
          unsigned hi = __shfl(pk[2 * kb + 1][w & 1], sl);
          pa[mi][kb].w[w] = (g >= 2) ? hi : lo;
        }
    }

    // O += P @ V_tile
#pragma unroll
    for (int kb = 0; kb < 2; ++kb) {
#pragma unroll
      for (int nh = 0; nh < 4; ++nh) {
        bf16x8 vf = *reinterpret_cast<const bf16x8*>(&vT[sw256(nh * 16 + lr, j * 64 + kb * 32 + g * 8)]);
#pragma unroll
        for (int mi = 0; mi < 2; ++mi)
          o[mi][nh] = __builtin_amdgcn_mfma_f32_16x16x32_bf16(pa[mi][kb].v, vf, o[mi][nh], 0, 0, 0);
      }
    }
  }

  // epilogue: normalize and store fp32 (l for q-row 16mi+4g+e lives at lane 4g+e)
  float* ob = out + (size_t)b * (T_DIM * H_DIM);
#pragma unroll
  for (int mi = 0; mi < 2; ++mi) {
    float linv[4];
#pragma unroll
    for (int e = 0; e < 4; ++e)
      linv[e] = 1.f / __shfl(l_run[mi], g * 4 + e);
#pragma unroll
    for (int nh = 0; nh < 4; ++nh)
#pragma unroll
      for (int e = 0; e < 4; ++e) {
        int r = r0 + mi * 16 + g * 4 + e;
        int h = nh * 16 + lr;
        ob[r * H_DIM + h] = o[mi][nh][e] * linv[e];
      }
  }
}

extern "C" void kernel_launch(void* const* d_in, const int* in_sizes, int n_in,
                              void* d_out, int out_size, void* d_ws, size_t ws_size,
                              hipStream_t stream) {
  const float* x  = (const float*)d_in[0];
  const float* Wk = (const float*)d_in[1];
  const float* Wq = (const float*)d_in[2];
  const float* Wv = (const float*)d_in[3];
  float* out = (float*)d_out;
  int B = in_sizes[0] / (T_DIM * C_DIM);   // 512
  head_fused<<<dim3(B), dim3(512), 0, stream>>>(x, Wk, Wq, Wv, out);
}

// Round 8
// 59.654 us; speedup vs baseline: 3.5351x; 3.5351x over previous
//
#include <hip/hip_runtime.h>

#define T_DIM 256
#define C_DIM 384
#define H_DIM 64

typedef __attribute__((ext_vector_type(4))) float f32x4;
typedef __attribute__((ext_vector_type(8))) short bf16x8;
typedef unsigned short u16;

// fp32 -> bf16 round-to-nearest-even (finite inputs)
__device__ __forceinline__ u16 f2b(float f) {
  unsigned u = __float_as_uint(f);
  u = (u + 0x7FFFu + ((u >> 16) & 1u)) >> 16;
  return (u16)u;
}
// packed f32x2 -> bf16x2: lo word = bf16(a), hi word = bf16(b)  (HW-verified R7)
__device__ __forceinline__ unsigned pkbf(float a, float b) {
  unsigned r;
  asm("v_cvt_pk_bf16_f32 %0, %1, %2" : "=v"(r) : "v"(a), "v"(b));
  return r;
}

// Swizzled element offsets (u16 units). Writes and reads share the permutation.
__device__ __forceinline__ int sw64(int r, int c)  { return r * 64  + (c ^ ((r & 7) << 3)); }
__device__ __forceinline__ int sw256(int h, int t) { return h * 256 + (t ^ ((h & 7) << 3)); }
__device__ __forceinline__ int sw32(int r, int c)  { return r * 32  + (c ^ (((r >> 1) & 3) << 3)); }

// One block per batch. 1024 threads = 16 waves -> 4 waves/SIMD at 1 block/CU.
// Per-thread QKV acc = 49152/1024 = 48 regs -> fits the 128-VGPR budget (no spill).
// Phase 1: QKV = x_b @ [Wq|Wk|Wv], M=256 N=192 K=384, K-step 32; wave wv owns
//   rows [16wv,16wv+16).  Phase 2: swapped-operand flash attention (R7-proven),
//   one 16-row strip per wave; per-SIMD causal work exactly balanced.
__global__ __launch_bounds__(1024, 4)
void head_fused(const float* __restrict__ x,
                const float* __restrict__ Wk,
                const float* __restrict__ Wq,
                const float* __restrict__ Wv,
                float* __restrict__ out)
{
  __shared__ u16 sh[32768];   // 64 KB union:
  // phase 1: xs = sh[0..8192) [256][32] sw32; wsT = sh[8192..14336) [192][32] sw32
  // handoff: per-wave Q slab at sh[wv*1024 .. +1024) [16][64] sw64 (32 KB total)
  // phase 2: ks = sh[0..16384) [256][64] sw64; vT = sh[16384..32768) [64][256] sw256
  u16* xs  = sh;
  u16* wsT = sh + 8192;
  u16* ks  = sh;
  u16* vT  = sh + 16384;

  const int tid  = threadIdx.x;
  const int wv   = tid >> 6;     // 0..15
  const int lane = tid & 63;
  const int g    = lane >> 4;
  const int lr   = lane & 15;
  const int b    = blockIdx.x;

  const float* xb = x + (size_t)b * (T_DIM * C_DIM);

  // ---------------- Phase 1: QKV projection ----------------
  // x staging: 2048 uint2-groups (4 floats) per K-chunk, 2 per thread
  int xr[2], xc[2];
#pragma unroll
  for (int it = 0; it < 2; ++it) {
    int idx = tid + it * 1024;
    xr[it] = idx >> 3;             // 0..255
    xc[it] = (idx & 7) * 4;        // 0..28
  }
  // W staging: 1536 tasks (row-quad q = idx>>5, col cc = idx&31, lane-consecutive)
  int wrow[2], wcc[2];
  const float* wsrc[2];
  bool wok[2];
#pragma unroll
  for (int it = 0; it < 2; ++it) {
    int idx = tid + it * 1024;
    wok[it] = (idx < 1536);        // wave-uniform (it=1: waves 8..15 idle)
    int q   = (idx >> 5) & 63;     // row-quad 0..47 (masked to keep indexing sane)
    int cc  = idx & 31;
    int seg = q >> 4;
    int hq  = q & 15;
    wrow[it] = seg * 64 + hq * 4;
    wcc[it]  = cc;
    wsrc[it] = ((seg == 0) ? Wq : (seg == 1) ? Wk : Wv) + hq * 4;
  }

  f32x4 acc[12];
#pragma unroll
  for (int nj = 0; nj < 12; ++nj)
    acc[nj] = (f32x4){0.f, 0.f, 0.f, 0.f};

  // prefetch chunk 0
  f32x4 px[2], pwv[2];
#pragma unroll
  for (int it = 0; it < 2; ++it)
    px[it] = *reinterpret_cast<const f32x4*>(xb + xr[it] * C_DIM + xc[it]);
#pragma unroll
  for (int it = 0; it < 2; ++it)
    if (wok[it])
      pwv[it] = *reinterpret_cast<const f32x4*>(wsrc[it] + wcc[it] * H_DIM);

  for (int kt = 0; kt < 12; ++kt) {
    __syncthreads();   // previous iteration's fragment reads done
#pragma unroll
    for (int it = 0; it < 2; ++it) {
      uint2 pv;
      pv.x = pkbf(px[it][0], px[it][1]);
      pv.y = pkbf(px[it][2], px[it][3]);
      *reinterpret_cast<uint2*>(&xs[sw32(xr[it], xc[it])]) = pv;
    }
#pragma unroll
    for (int it = 0; it < 2; ++it)
      if (wok[it]) {
        wsT[sw32(wrow[it] + 0, wcc[it])] = f2b(pwv[it][0]);
        wsT[sw32(wrow[it] + 1, wcc[it])] = f2b(pwv[it][1]);
        wsT[sw32(wrow[it] + 2, wcc[it])] = f2b(pwv[it][2]);
        wsT[sw32(wrow[it] + 3, wcc[it])] = f2b(pwv[it][3]);
      }
    // prefetch next K-chunk (hides under MFMA section)
    if (kt < 11) {
      int kk = (kt + 1) * 32;
#pragma unroll
      for (int it = 0; it < 2; ++it)
        px[it] = *reinterpret_cast<const f32x4*>(xb + xr[it] * C_DIM + kk + xc[it]);
#pragma unroll
      for (int it = 0; it < 2; ++it)
        if (wok[it])
          pwv[it] = *reinterpret_cast<const f32x4*>(wsrc[it] + (kk + wcc[it]) * H_DIM);
    }
    __syncthreads();

    // MFMA: wave wv computes rows [16wv, 16wv+16), all 192 N cols
    bf16x8 afr = *reinterpret_cast<const bf16x8*>(&xs[sw32(wv * 16 + lr, g * 8)]);
#pragma unroll
    for (int nj = 0; nj < 12; ++nj) {
      bf16x8 bfr = *reinterpret_cast<const bf16x8*>(&wsT[sw32(nj * 16 + lr, g * 8)]);
      acc[nj] = __builtin_amdgcn_mfma_f32_16x16x32_bf16(afr, bfr, acc[nj], 0, 0, 0);
    }
  }

  // ---------------- Handoff ----------------
  __syncthreads();   // all staging reads done; staging region now dead

  // (1) own Q rows D->slab (acc nj 0..3 hold Q[16wv + 4g+e][16nj+lr])
  u16* slab = sh + wv * 1024;   // [16][64] sw64, wave-private
#pragma unroll
  for (int nj = 0; nj < 4; ++nj)
#pragma unroll
    for (int e = 0; e < 4; ++e)
      slab[sw64(g * 4 + e, nj * 16 + lr)] = f2b(acc[nj][e]);
  asm volatile("s_waitcnt lgkmcnt(0)" ::: "memory");

  // (2) read Q as B-fragments: qf[kb][e] = Q[16wv+lr][32kb+8g+e]
  bf16x8 qf[2];
#pragma unroll
  for (int kb = 0; kb < 2; ++kb)
    qf[kb] = *reinterpret_cast<const bf16x8*>(&slab[sw64(lr, kb * 32 + g * 8)]);
  __syncthreads();   // all slab reads done before K/V scatter overwrites region

  // (3) scatter K,V fragments (acc nj 4..11) into ks/vT
#pragma unroll
  for (int nj = 4; nj < 12; ++nj)
#pragma unroll
    for (int e = 0; e < 4; ++e) {
      int r = wv * 16 + g * 4 + e;
      int n = nj * 16 + lr;
      u16 val = f2b(acc[nj][e]);
      if (n < 128) ks[sw64(r, n - 64)] = val;
      else         vT[sw256(n - 128, r)] = val;
    }
  __syncthreads();

  // ---------------- Phase 2: swapped-operand causal flash attention ----------------
  const int r0   = wv * 16;
  const int jmax = wv >> 2;   // per-SIMD tile totals balanced: {1,2,3,4} per SIMD

  f32x4 o[4];                 // O D-layout: row q-local = 4g+e, col h = 16nh+lr
  float m_run = -__builtin_inff(), l_run = 0.f;   // per-lane stats for q = r0+lr
#pragma unroll
  for (int nh = 0; nh < 4; ++nh) o[nh] = (f32x4){0.f, 0.f, 0.f, 0.f};

  for (int j = 0; j <= jmax; ++j) {
    // S^T tile: sT[ni][e] = S[q = r0+lr][kv = 64j+16ni+4g+e]
    f32x4 sT[4];
#pragma unroll
    for (int ni = 0; ni < 4; ++ni) sT[ni] = (f32x4){0.f, 0.f, 0.f, 0.f};
#pragma unroll
    for (int kb = 0; kb < 2; ++kb) {
#pragma unroll
      for (int ni = 0; ni < 4; ++ni) {
        bf16x8 kf = *reinterpret_cast<const bf16x8*>(&ks[sw64(j * 64 + ni * 16 + lr, kb * 32 + g * 8)]);
        sT[ni] = __builtin_amdgcn_mfma_f32_16x16x32_bf16(kf, qf[kb], sT[ni], 0, 0, 0);
      }
    }

    // scale + causal mask + per-lane-q softmax
    const int q = r0 + lr;
    float pm = -__builtin_inff();
#pragma unroll
    for (int ni = 0; ni < 4; ++ni)
#pragma unroll
      for (int e = 0; e < 4; ++e) {
        float v = sT[ni][e] * 0.125f;
        int kv = j * 64 + ni * 16 + g * 4 + e;
        v = (kv > q) ? -__builtin_inff() : v;
        sT[ni][e] = v;
        pm = fmaxf(pm, v);
      }
    pm = fmaxf(pm, __shfl_xor(pm, 16));
    pm = fmaxf(pm, __shfl_xor(pm, 32));

    float mn = fmaxf(m_run, pm);
    float alpha = __expf(m_run - mn);   // first tile: exp(-inf)=0
    m_run = mn;
    float rs = 0.f;
#pragma unroll
    for (int ni = 0; ni < 4; ++ni)
#pragma unroll
      for (int e = 0; e < 4; ++e) {
        float p = __expf(sT[ni][e] - mn);  // masked: exp(-inf)=0
        sT[ni][e] = p;
        rs += p;
      }
    rs += __shfl_xor(rs, 16);
    rs += __shfl_xor(rs, 32);
    l_run = l_run * alpha + rs;

    // rescale O (alpha for q-row 4g+e lives at lane 4g+e within the 16-group)
#pragma unroll
    for (int e = 0; e < 4; ++e) {
      float am = __shfl(alpha, g * 4 + e);
#pragma unroll
      for (int nh = 0; nh < 4; ++nh) o[nh][e] *= am;
    }

    // P D->A transpose via g-group shfl exchange (R7-proven map)
    union PA { unsigned w[4]; bf16x8 v; };
    PA pa[2];
    unsigned pk[4][2];
#pragma unroll
    for (int ni = 0; ni < 4; ++ni) {
      pk[ni][0] = pkbf(sT[ni][0], sT[ni][1]);  // kv {16ni+4g+0, +1}
      pk[ni][1] = pkbf(sT[ni][2], sT[ni][3]);  // kv {16ni+4g+2, +3}
    }
#pragma unroll
    for (int kb = 0; kb < 2; ++kb)
#pragma unroll
      for (int w = 0; w < 4; ++w) {
        int sl = ((2 * g + (w >> 1)) & 3) * 16 + lr;   // source lane
        unsigned lo = __shfl(pk[2 * kb + 0][w & 1], sl);
        unsigned hi = __shfl(pk[2 * kb + 1][w & 1], sl);
        pa[kb].w[w] = (g >= 2) ? hi : lo;
      }

    // O += P @ V_tile
#pragma unroll
    for (int kb = 0; kb < 2; ++kb) {
#pragma unroll
      for (int nh = 0; nh < 4; ++nh) {
        bf16x8 vf = *reinterpret_cast<const bf16x8*>(&vT[sw256(nh * 16 + lr, j * 64 + kb * 32 + g * 8)]);
        o[nh] = __builtin_amdgcn_mfma_f32_16x16x32_bf16(pa[kb].v, vf, o[nh], 0, 0, 0);
      }
    }
  }

  // epilogue: normalize and store fp32 (l for q-row 4g+e lives at lane 4g+e)
  float* ob = out + (size_t)b * (T_DIM * H_DIM);
  float linv[4];
#pragma unroll
  for (int e = 0; e < 4; ++e)
    linv[e] = 1.f / __shfl(l_run, g * 4 + e);
#pragma unroll
  for (int nh = 0; nh < 4; ++nh)
#pragma unroll
    for (int e = 0; e < 4; ++e) {
      int r = r0 + g * 4 + e;
      int h = nh * 16 + lr;
      ob[r * H_DIM + h] = o[nh][e] * linv[e];
    }
}

extern "C" void kernel_launch(void* const* d_in, const int* in_sizes, int n_in,
                              void* d_out, int out_size, void* d_ws, size_t ws_size,
                              hipStream_t stream) {
  const float* x  = (const float*)d_in[0];
  const float* Wk = (const float*)d_in[1];
  const float* Wq = (const float*)d_in[2];
  const float* Wv = (const float*)d_in[3];
  float* out = (float*)d_out;
  int B = in_sizes[0] / (T_DIM * C_DIM);   // 512
  head_fused<<<dim3(B), dim3(1024), 0, stream>>>(x, Wk, Wq, Wv, out);
}